// Round 12
// baseline (143.698 us; speedup 1.0000x reference)
//
#include <hip/hip_runtime.h>

// N=100000 nodes, D=64, P=Q=32, E=3200000 edges.
// Pipeline: intensity -> {bf16, fp8-e4m3} copies -> bucket partition (radix
// by dst>>7, 512 partition blocks = full wave capacity) -> in-place node
// sort -> per-node CSR gather on fp8 rows (L2-resident) -> MFMA node kernel,
// zero-LDS D-fragment epilogue.

#define RLOG 7
#define RNODES 128
#define NBLK 512
#define CAP 6144

typedef __attribute__((ext_vector_type(8))) short short8;
typedef __attribute__((ext_vector_type(4))) float f32x4;
typedef __attribute__((ext_vector_type(2))) float f32x2;

__device__ __forceinline__ unsigned short f2bf(float x) {
    union { float f; unsigned u; } v; v.f = x;
    unsigned r = v.u + 0x7FFF + ((v.u >> 16) & 1);  // RNE
    return (unsigned short)(r >> 16);
}

__device__ __forceinline__ float bf2f(unsigned short b) {
    union { unsigned u; float f; } v; v.u = ((unsigned)b) << 16;
    return v.f;
}

// ---- fp8 pack/unpack: prefer HW cvt (self-consistent encode/decode) ----
#if __has_builtin(__builtin_amdgcn_cvt_pk_fp8_f32) && __has_builtin(__builtin_amdgcn_cvt_pk_f32_fp8)
__device__ __forceinline__ unsigned pack4_fp8(float a, float b, float c, float d) {
    int p = __builtin_amdgcn_cvt_pk_fp8_f32(a, b, 0, false);
    p = __builtin_amdgcn_cvt_pk_fp8_f32(c, d, p, true);
    return (unsigned)p;
}
__device__ __forceinline__ void unpack4_fp8(unsigned w, float& a, float& b, float& c, float& d) {
    f32x2 lo = __builtin_amdgcn_cvt_pk_f32_fp8(w, false);
    f32x2 hi = __builtin_amdgcn_cvt_pk_f32_fp8(w, true);
    a = lo[0]; b = lo[1]; c = hi[0]; d = hi[1];
}
#else
__device__ __forceinline__ unsigned char f2fp8_sw(float x) {
    union { float f; unsigned u; } v; v.f = x;
    unsigned s = (v.u >> 24) & 0x80;
    float ax = fminf(fabsf(x), 448.0f);
    union { float f; unsigned u; } w; w.f = ax;
    int e = (int)((w.u >> 23) & 0xFF) - 127;
    if (e < -6) {
        int mi = (int)(ax * 512.0f + 0.5f);
        if (mi > 7) mi = 7;
        return (unsigned char)(s | mi);
    }
    unsigned mant = (w.u >> 20) & 7;
    unsigned rest = w.u & 0xFFFFF;
    unsigned rnd = (rest > 0x80000u) || (rest == 0x80000u && (mant & 1));
    unsigned enc = ((unsigned)(e + 7) << 3) | mant;
    enc += rnd;
    if (enc > 0x7Eu) enc = 0x7Eu;
    return (unsigned char)(s | enc);
}
__device__ __forceinline__ float fp82f_sw(unsigned char b) {
    unsigned e = (b >> 3) & 0xF, m = b & 7;
    float mag;
    if (e == 0) mag = (float)m * 0.001953125f;
    else {
        union { unsigned u; float f; } v;
        v.u = ((e + 120u) << 23) | (m << 20);
        mag = v.f;
    }
    return (b & 0x80) ? -mag : mag;
}
__device__ __forceinline__ unsigned pack4_fp8(float a, float b, float c, float d) {
    return (unsigned)f2fp8_sw(a) | ((unsigned)f2fp8_sw(b) << 8) |
           ((unsigned)f2fp8_sw(c) << 16) | ((unsigned)f2fp8_sw(d) << 24);
}
__device__ __forceinline__ void unpack4_fp8(unsigned w, float& a, float& b, float& c, float& d) {
    a = fp82f_sw((unsigned char)(w & 0xFF));
    b = fp82f_sw((unsigned char)((w >> 8) & 0xFF));
    c = fp82f_sw((unsigned char)((w >> 16) & 0xFF));
    d = fp82f_sw((unsigned char)((w >> 24) & 0xFF));
}
#endif

__device__ __forceinline__ float softplus_fast(float x) {
    float t = __expf(-fabsf(x));
    return fmaxf(x, 0.0f) + __logf(1.0f + t);
}

__device__ __forceinline__ float tanh_fast(float x) {
    float t = __expf(-2.0f * fabsf(x));
    float m = (1.0f - t) * __builtin_amdgcn_rcpf(1.0f + t);
    return __builtin_copysignf(m, x);
}

__device__ __forceinline__ int chunk_of(int E) {
    return (((E + NBLK - 1) / NBLK) + 3) & ~3;
}

// ---- 0. intensity -> bf16 + fp8 copies
__global__ __launch_bounds__(256) void cvt_int(const float* __restrict__ x,
                                               unsigned short* __restrict__ ybf,
                                               unsigned* __restrict__ yfp8,
                                               int total4) {
    int t0 = blockIdx.x * 256 + threadIdx.x;
    int stride = gridDim.x * 256;
    for (int i = t0; i < total4; i += stride) {
        float4 v = ((const float4*)x)[i];
        ushort4 r;
        r.x = f2bf(v.x); r.y = f2bf(v.y); r.z = f2bf(v.z); r.w = f2bf(v.w);
        ((ushort4*)ybf)[i] = r;
        yfp8[i] = pack4_fp8(v.x, v.y, v.z, v.w);
    }
}

// ---- 1. per-block bucket histogram: cnt[b*NBLK + blk]
__global__ __launch_bounds__(1024) void bin_count(const int* __restrict__ edst,
                                                  int* __restrict__ cnt,
                                                  int E, int B) {
    __shared__ int lcnt[1024];
    int tid = threadIdx.x, blk = blockIdx.x;
    for (int b = tid; b < B; b += 1024) lcnt[b] = 0;
    __syncthreads();
    int chunk = chunk_of(E);
    int start = blk * chunk;
    int end = min(E, start + chunk);
    int v4s = start >> 2, v4e = end >> 2;
    for (int i = v4s + tid; i < v4e; i += 1024) {
        int4 d = ((const int4*)edst)[i];
        atomicAdd(&lcnt[d.x >> RLOG], 1);
        atomicAdd(&lcnt[d.y >> RLOG], 1);
        atomicAdd(&lcnt[d.z >> RLOG], 1);
        atomicAdd(&lcnt[d.w >> RLOG], 1);
    }
    for (int i = (v4e << 2) + tid; i < end; i += 1024)
        atomicAdd(&lcnt[edst[i] >> RLOG], 1);
    __syncthreads();
    for (int b = tid; b < B; b += 1024) cnt[b * NBLK + blk] = lcnt[b];
}

// ---- 2a. per-block partial sums
__global__ __launch_bounds__(1024) void scan_reduce(const int* __restrict__ cnt,
                                                    int* __restrict__ bsum, int M) {
    int idx = blockIdx.x * 1024 + threadIdx.x;
    int v = (idx < M) ? cnt[idx] : 0;
    #pragma unroll
    for (int off = 32; off; off >>= 1) v += __shfl_xor(v, off);
    __shared__ int wtot[16];
    int lane = threadIdx.x & 63, wave = threadIdx.x >> 6;
    if (lane == 0) wtot[wave] = v;
    __syncthreads();
    if (threadIdx.x == 0) {
        int s = 0;
        #pragma unroll
        for (int i = 0; i < 16; ++i) s += wtot[i];
        bsum[blockIdx.x] = s;
    }
}

// ---- 2b. exclusive scan of block sums (single block, nb <= 1024)
__global__ __launch_bounds__(1024) void scan_top(int* __restrict__ bsum, int nb) {
    int t = threadIdx.x;
    int lane = t & 63, wave = t >> 6;
    int v = (t < nb) ? bsum[t] : 0;
    int incl = v;
    #pragma unroll
    for (int off = 1; off < 64; off <<= 1) {
        int w = __shfl_up(incl, off);
        if (lane >= off) incl += w;
    }
    __shared__ int wt[16];
    if (lane == 63) wt[wave] = incl;
    __syncthreads();
    int woff = 0;
    for (int i = 0; i < wave; ++i) woff += wt[i];
    if (t < nb) bsum[t] = woff + incl - v;
}

// ---- 2c. final exclusive scan -> offs
__global__ __launch_bounds__(1024) void scan_final(const int* __restrict__ cnt,
                                                   const int* __restrict__ bsum,
                                                   int* __restrict__ offs, int M) {
    int t = threadIdx.x;
    int idx = blockIdx.x * 1024 + t;
    int lane = t & 63, wave = t >> 6;
    int v = (idx < M) ? cnt[idx] : 0;
    int incl = v;
    #pragma unroll
    for (int off = 1; off < 64; off <<= 1) {
        int w = __shfl_up(incl, off);
        if (lane >= off) incl += w;
    }
    __shared__ int wtot[16];
    if (lane == 63) wtot[wave] = incl;
    __syncthreads();
    int woff = 0;
    for (int i = 0; i < wave; ++i) woff += wtot[i];
    if (idx < M) offs[idx] = bsum[blockIdx.x] + woff + incl - v;
}

// ---- 3. scatter packed entries using LDS cursors (int4 edge loads)
__global__ __launch_bounds__(1024) void bin_scatter(const int* __restrict__ esrc,
                                                    const int* __restrict__ edst,
                                                    const int* __restrict__ offs,
                                                    int* __restrict__ binned,
                                                    int E, int B) {
    __shared__ int lcur[1024];
    int tid = threadIdx.x, blk = blockIdx.x;
    for (int b = tid; b < B; b += 1024) lcur[b] = offs[b * NBLK + blk];
    __syncthreads();
    int chunk = chunk_of(E);
    int start = blk * chunk;
    int end = min(E, start + chunk);
    int v4s = start >> 2, v4e = end >> 2;
    for (int i = v4s + tid; i < v4e; i += 1024) {
        int4 d = ((const int4*)edst)[i];
        int4 s = ((const int4*)esrc)[i];
        int p0 = atomicAdd(&lcur[d.x >> RLOG], 1);
        int p1 = atomicAdd(&lcur[d.y >> RLOG], 1);
        int p2 = atomicAdd(&lcur[d.z >> RLOG], 1);
        int p3 = atomicAdd(&lcur[d.w >> RLOG], 1);
        binned[p0] = ((d.x & (RNODES - 1)) << 17) | s.x;
        binned[p1] = ((d.y & (RNODES - 1)) << 17) | s.y;
        binned[p2] = ((d.z & (RNODES - 1)) << 17) | s.z;
        binned[p3] = ((d.w & (RNODES - 1)) << 17) | s.w;
    }
    for (int i = (v4e << 2) + tid; i < end; i += 1024) {
        int d = edst[i];
        int s = esrc[i];
        int pos = atomicAdd(&lcur[d >> RLOG], 1);
        binned[pos] = ((d & (RNODES - 1)) << 17) | s;
    }
}

// ---- 4. in-place node sort within each bucket
__global__ __launch_bounds__(256) void node_sort(int* __restrict__ binned,
                                                 const int* __restrict__ offs,
                                                 int* __restrict__ nodestart,
                                                 int* __restrict__ degarr,
                                                 int E, int N, int B) {
    __shared__ int sl[CAP];
    __shared__ int c128[RNODES];
    __shared__ int pos[RNODES];
    int tid = threadIdx.x;
    int b = blockIdx.x;
    int start = offs[b * NBLK];
    int end = (b + 1 < B) ? offs[(b + 1) * NBLK] : E;
    int m = min(end - start, CAP);

    for (int i = tid; i < m; i += 256) sl[i] = binned[start + i];
    if (tid < RNODES) c128[tid] = 0;
    __syncthreads();
    for (int i = tid; i < m; i += 256) atomicAdd(&c128[sl[i] >> 17], 1);
    __syncthreads();

    int x = 0, incl = 0;
    if (tid < RNODES) { x = c128[tid]; incl = x; }
    #pragma unroll
    for (int off = 1; off < RNODES; off <<= 1) {
        int y = 0;
        if (tid < RNODES && tid >= off) y = c128[tid - off];
        __syncthreads();
        if (tid < RNODES) { incl += y; c128[tid] = incl; }
        __syncthreads();
    }
    if (tid < RNODES) {
        int excl = incl - x;
        pos[tid] = excl;
        int node = b * RNODES + tid;
        if (node < N) {
            nodestart[node] = start + excl;
            degarr[node] = x;
        }
    }
    __syncthreads();
    for (int i = tid; i < m; i += 256) {
        int e = sl[i];
        int p = atomicAdd(&pos[e >> 17], 1);
        binned[start + p] = e & 131071;
    }
}

// ---- 5. gather on fp8 rows (32B, L2-resident): 8 lanes/edge, unroll 4
__global__ __launch_bounds__(256) void gather_kernel(
    const unsigned* __restrict__ ifp8, const int* __restrict__ binned,
    const int* __restrict__ nodestart, const int* __restrict__ degarr,
    unsigned short* __restrict__ xnbr, int N) {
    int lane = threadIdx.x & 63;
    int wave = threadIdx.x >> 6;
    int gid = lane >> 3;       // 8 groups of 8 lanes
    int fl = lane & 7;         // uint index within the 32-feature fp8 row
    int gwave = blockIdx.x * 4 + wave;
    int wstride = gridDim.x * 4;
    for (int n = gwave; n < N; n += wstride) {
        int st = nodestart[n];
        int dg = degarr[n];
        float a0 = 0.f, a1 = 0.f, a2 = 0.f, a3 = 0.f;
        int j = gid;
        for (; j + 24 < dg; j += 32) {
            int s0 = binned[st + j];
            int s1 = binned[st + j + 8];
            int s2 = binned[st + j + 16];
            int s3 = binned[st + j + 24];
            unsigned w0 = ifp8[(size_t)s0 * 8 + fl];
            unsigned w1 = ifp8[(size_t)s1 * 8 + fl];
            unsigned w2 = ifp8[(size_t)s2 * 8 + fl];
            unsigned w3 = ifp8[(size_t)s3 * 8 + fl];
            float x0, x1, x2, x3;
            unpack4_fp8(w0, x0, x1, x2, x3);
            a0 += x0; a1 += x1; a2 += x2; a3 += x3;
            unpack4_fp8(w1, x0, x1, x2, x3);
            a0 += x0; a1 += x1; a2 += x2; a3 += x3;
            unpack4_fp8(w2, x0, x1, x2, x3);
            a0 += x0; a1 += x1; a2 += x2; a3 += x3;
            unpack4_fp8(w3, x0, x1, x2, x3);
            a0 += x0; a1 += x1; a2 += x2; a3 += x3;
        }
        for (; j < dg; j += 8) {
            int s0 = binned[st + j];
            unsigned w0 = ifp8[(size_t)s0 * 8 + fl];
            float x0, x1, x2, x3;
            unpack4_fp8(w0, x0, x1, x2, x3);
            a0 += x0; a1 += x1; a2 += x2; a3 += x3;
        }
        #pragma unroll
        for (int off = 8; off < 64; off <<= 1) {
            a0 += __shfl_xor(a0, off);
            a1 += __shfl_xor(a1, off);
            a2 += __shfl_xor(a2, off);
            a3 += __shfl_xor(a3, off);
        }
        if (lane < 8) {
            float inv = (dg > 0) ? 1.0f / (float)dg : 0.0f;
            ushort4 r;
            r.x = f2bf(a0 * inv); r.y = f2bf(a1 * inv);
            r.z = f2bf(a2 * inv); r.w = f2bf(a3 * inv);
            ((ushort4*)xnbr)[(size_t)n * 8 + fl] = r;
        }
    }
}

// ---- 6. build stacked bf16 weight matrix Wbig[192][64]
__global__ __launch_bounds__(256) void prep_w(const float* __restrict__ Wf,
                                              const float* __restrict__ Wg,
                                              const float* __restrict__ Wz,
                                              const float* __restrict__ WA,
                                              unsigned short* __restrict__ wbig) {
    int idx = blockIdx.x * 256 + threadIdx.x;
    if (idx >= 192 * 64) return;
    int r = idx >> 6, k = idx & 63;
    float v = (r < 64)  ? Wf[r * 64 + k]
            : (r < 128) ? Wg[(r - 64) * 64 + k]
            : (r < 160) ? Wz[(r - 128) * 64 + k]
                        : WA[(r - 160) * 64 + k];
    wbig[idx] = f2bf(v);
}

// ---- 7. MFMA node kernel, zero-LDS epilogue in D-fragment layout.
__global__ __launch_bounds__(256, 4) void node_mfma(
    const float* __restrict__ u,
    const unsigned short* __restrict__ ibf,
    const unsigned short* __restrict__ xnbr,
    const unsigned short* __restrict__ wbig,
    const float* __restrict__ bfp, const float* __restrict__ bgp,
    const float* __restrict__ bzp, const float* __restrict__ bAp,
    float* __restrict__ out, int N) {
    int tid = threadIdx.x;
    int lane = tid & 63;
    int wave = tid >> 6;
    int tile = blockIdx.x * 4 + wave;
    int ntiles = N >> 4;
    if (tile >= ntiles) return;

    int col = lane & 15;
    int kg = lane >> 4;
    int n0 = tile * 16;
    int node = n0 + col;

    const float* ub = u + (size_t)node * 64 + kg * 8;
    float4 u0 = *(const float4*)(ub);
    float4 u1 = *(const float4*)(ub + 4);
    float4 u2 = *(const float4*)(ub + 32);
    float4 u3 = *(const float4*)(ub + 36);
    short8 au0, au1;
    au0[0]=(short)f2bf(u0.x); au0[1]=(short)f2bf(u0.y); au0[2]=(short)f2bf(u0.z); au0[3]=(short)f2bf(u0.w);
    au0[4]=(short)f2bf(u1.x); au0[5]=(short)f2bf(u1.y); au0[6]=(short)f2bf(u1.z); au0[7]=(short)f2bf(u1.w);
    au1[0]=(short)f2bf(u2.x); au1[1]=(short)f2bf(u2.y); au1[2]=(short)f2bf(u2.z); au1[3]=(short)f2bf(u2.w);
    au1[4]=(short)f2bf(u3.x); au1[5]=(short)f2bf(u3.y); au1[6]=(short)f2bf(u3.z); au1[7]=(short)f2bf(u3.w);
    short8 ax0 = *(const short8*)(ibf  + (size_t)node * 32 + kg * 8);
    short8 ax1 = *(const short8*)(xnbr + (size_t)node * 32 + kg * 8);

    const short8* wb = (const short8*)wbig;
    f32x4 acc[12];
    #pragma unroll
    for (int t = 0; t < 12; ++t) acc[t] = (f32x4){0.f, 0.f, 0.f, 0.f};
    #pragma unroll
    for (int t = 0; t < 12; ++t) {
        short8 a0 = (t < 10) ? au0 : ax0;
        short8 a1 = (t < 10) ? au1 : ax1;
        short8 b0 = wb[(t * 16 + col) * 8 + kg];
        short8 b1 = wb[(t * 16 + col) * 8 + 4 + kg];
        acc[t] = __builtin_amdgcn_mfma_f32_16x16x32_bf16(a0, b0, acc[t], 0, 0, 0);
        acc[t] = __builtin_amdgcn_mfma_f32_16x16x32_bf16(a1, b1, acc[t], 0, 0, 0);
    }

    float bfv[4], bgv[4], bzv[4];
    #pragma unroll
    for (int s = 0; s < 4; ++s) {
        int j = s * 16 + col;
        bfv[s] = bfp[j];
        bgv[s] = bgp[j];
        bzv[s] = (s < 2) ? bzp[j] : bAp[j - 32];
    }

    float du01[2][4], uv01[2][4];
    float ar[4], br[4];
    #pragma unroll
    for (int r = 0; r < 4; ++r) { ar[r] = 0.f; br[r] = 0.f; }
    #pragma unroll
    for (int s = 0; s < 2; ++s) {
        #pragma unroll
        for (int r = 0; r < 4; ++r) {
            int nd = n0 + kg * 4 + r;
            float uu = u[(size_t)nd * 64 + s * 16 + col];
            float fpre = acc[s][r] + bfv[s];
            float gpre = acc[4 + s][r] + bgv[s];
            float zpre = acc[8 + s][r] + bzv[s];
            float Fu = softplus_fast(fpre);
            float Gu = softplus_fast(gpre);
            float zv = tanh_fast(zpre);
            float d = -Fu * uu + Gu * zv;
            du01[s][r] = d;
            uv01[s][r] = uu;
            ar[r] = fmaf(d, uu, ar[r]);
            br[r] = fmaf(uu, uu, br[r]);
        }
    }
    #pragma unroll
    for (int off = 1; off < 16; off <<= 1) {
        #pragma unroll
        for (int r = 0; r < 4; ++r) {
            ar[r] += __shfl_xor(ar[r], off);
            br[r] += __shfl_xor(br[r], off);
        }
    }
    float coef[4];
    #pragma unroll
    for (int r = 0; r < 4; ++r) coef[r] = ar[r] * __builtin_amdgcn_rcpf(br[r]);

    #pragma unroll
    for (int s = 0; s < 2; ++s) {
        #pragma unroll
        for (int r = 0; r < 4; ++r) {
            int nd = n0 + kg * 4 + r;
            out[(size_t)nd * 64 + s * 16 + col] = du01[s][r] - coef[r] * uv01[s][r];
        }
    }
    #pragma unroll
    for (int s = 2; s < 4; ++s) {
        #pragma unroll
        for (int r = 0; r < 4; ++r) {
            int nd = n0 + kg * 4 + r;
            float uu = u[(size_t)nd * 64 + s * 16 + col];
            float fpre = acc[s][r] + bfv[s];
            float gpre = acc[4 + s][r] + bgv[s];
            float zpre = acc[8 + s][r] + bzv[s];
            float Fu = softplus_fast(fpre);
            float Gu = softplus_fast(gpre);
            float zv = fmaxf(zpre, 0.0f);
            out[(size_t)nd * 64 + s * 16 + col] = -Fu * uu + Gu * zv;
        }
    }
}

extern "C" void kernel_launch(void* const* d_in, const int* in_sizes, int n_in,
                              void* d_out, int out_size, void* d_ws, size_t ws_size,
                              hipStream_t stream) {
    const float* u         = (const float*)d_in[0];
    const float* intensity = (const float*)d_in[1];
    const int*   esrc      = (const int*)d_in[2];
    const int*   edst      = (const int*)d_in[3];
    const float* Wf        = (const float*)d_in[4];
    const float* bf        = (const float*)d_in[5];
    const float* Wg        = (const float*)d_in[6];
    const float* bg        = (const float*)d_in[7];
    const float* Wz        = (const float*)d_in[8];
    const float* bz        = (const float*)d_in[9];
    const float* WA        = (const float*)d_in[10];
    const float* bA        = (const float*)d_in[11];

    int N = in_sizes[0] / 64;
    int E = in_sizes[2];
    int B = (N + RNODES - 1) / RNODES;          // 782
    int M = B * NBLK;                            // 400384
    int nb = (M + 1023) / 1024;                  // 391 (<=1024)

    int* cnt       = (int*)d_ws;                 // M
    int* offs      = cnt + M;                    // M
    int* bsum      = offs + M;                   // 1024
    int* binned    = bsum + 1024;                // E
    int* nodestart = binned + E;                 // N
    int* degarr    = nodestart + N;              // N
    unsigned short* xnbr = (unsigned short*)(degarr + N);   // N*32
    unsigned short* wbig = xnbr + (size_t)N * 32;           // 192*64
    unsigned short* ibf  = wbig + 192 * 64;                 // N*32
    unsigned* ifp8 = (unsigned*)(ibf + (size_t)N * 32);     // N*8 uints

    cvt_int<<<2048, 256, 0, stream>>>(intensity, ibf, ifp8, N * 8);
    prep_w<<<48, 256, 0, stream>>>(Wf, Wg, Wz, WA, wbig);
    bin_count<<<NBLK, 1024, 0, stream>>>(edst, cnt, E, B);
    scan_reduce<<<nb, 1024, 0, stream>>>(cnt, bsum, M);
    scan_top<<<1, 1024, 0, stream>>>(bsum, nb);
    scan_final<<<nb, 1024, 0, stream>>>(cnt, bsum, offs, M);
    bin_scatter<<<NBLK, 1024, 0, stream>>>(esrc, edst, offs, binned, E, B);
    node_sort<<<B, 256, 0, stream>>>(binned, offs, nodestart, degarr, E, N, B);
    gather_kernel<<<2048, 256, 0, stream>>>(ifp8, binned, nodestart, degarr,
                                            xnbr, N);
    int ntiles = N / 16;
    int nblocks = (ntiles + 3) / 4;
    node_mfma<<<nblocks, 256, 0, stream>>>(u, ibf, xnbr, wbig,
                                           bf, bg, bz, bA, (float*)d_out, N);
}

// Round 13
// 131.023 us; speedup vs baseline: 1.0967x; 1.0967x over previous
//
#include <hip/hip_runtime.h>

// N=100000 nodes, D=64, P=Q=32, E=3200000 edges.
// Pipeline: intensity -> {bf16, fp8-e4m3} copies -> bucket partition (radix
// by dst>>7, 512 blocks; scatter via LDS-staged block-local counting sort ->
// fully coalesced writes) -> in-place node sort -> per-node CSR gather on
// fp8 rows (L2-resident) -> MFMA node kernel, zero-LDS D-fragment epilogue.

#define RLOG 7
#define RNODES 128
#define NBLK 512
#define CAP 6144
#define CHUNK 6272   // >= ceil4(E/NBLK) = 6252

typedef __attribute__((ext_vector_type(8))) short short8;
typedef __attribute__((ext_vector_type(4))) float f32x4;
typedef __attribute__((ext_vector_type(2))) float f32x2;

__device__ __forceinline__ unsigned short f2bf(float x) {
    union { float f; unsigned u; } v; v.f = x;
    unsigned r = v.u + 0x7FFF + ((v.u >> 16) & 1);  // RNE
    return (unsigned short)(r >> 16);
}

__device__ __forceinline__ float bf2f(unsigned short b) {
    union { unsigned u; float f; } v; v.u = ((unsigned)b) << 16;
    return v.f;
}

// ---- fp8 pack/unpack: prefer HW cvt (self-consistent encode/decode) ----
#if __has_builtin(__builtin_amdgcn_cvt_pk_fp8_f32) && __has_builtin(__builtin_amdgcn_cvt_pk_f32_fp8)
__device__ __forceinline__ unsigned pack4_fp8(float a, float b, float c, float d) {
    int p = __builtin_amdgcn_cvt_pk_fp8_f32(a, b, 0, false);
    p = __builtin_amdgcn_cvt_pk_fp8_f32(c, d, p, true);
    return (unsigned)p;
}
__device__ __forceinline__ void unpack4_fp8(unsigned w, float& a, float& b, float& c, float& d) {
    f32x2 lo = __builtin_amdgcn_cvt_pk_f32_fp8(w, false);
    f32x2 hi = __builtin_amdgcn_cvt_pk_f32_fp8(w, true);
    a = lo[0]; b = lo[1]; c = hi[0]; d = hi[1];
}
#else
__device__ __forceinline__ unsigned char f2fp8_sw(float x) {
    union { float f; unsigned u; } v; v.f = x;
    unsigned s = (v.u >> 24) & 0x80;
    float ax = fminf(fabsf(x), 448.0f);
    union { float f; unsigned u; } w; w.f = ax;
    int e = (int)((w.u >> 23) & 0xFF) - 127;
    if (e < -6) {
        int mi = (int)(ax * 512.0f + 0.5f);
        if (mi > 7) mi = 7;
        return (unsigned char)(s | mi);
    }
    unsigned mant = (w.u >> 20) & 7;
    unsigned rest = w.u & 0xFFFFF;
    unsigned rnd = (rest > 0x80000u) || (rest == 0x80000u && (mant & 1));
    unsigned enc = ((unsigned)(e + 7) << 3) | mant;
    enc += rnd;
    if (enc > 0x7Eu) enc = 0x7Eu;
    return (unsigned char)(s | enc);
}
__device__ __forceinline__ float fp82f_sw(unsigned char b) {
    unsigned e = (b >> 3) & 0xF, m = b & 7;
    float mag;
    if (e == 0) mag = (float)m * 0.001953125f;
    else {
        union { unsigned u; float f; } v;
        v.u = ((e + 120u) << 23) | (m << 20);
        mag = v.f;
    }
    return (b & 0x80) ? -mag : mag;
}
__device__ __forceinline__ unsigned pack4_fp8(float a, float b, float c, float d) {
    return (unsigned)f2fp8_sw(a) | ((unsigned)f2fp8_sw(b) << 8) |
           ((unsigned)f2fp8_sw(c) << 16) | ((unsigned)f2fp8_sw(d) << 24);
}
__device__ __forceinline__ void unpack4_fp8(unsigned w, float& a, float& b, float& c, float& d) {
    a = fp82f_sw((unsigned char)(w & 0xFF));
    b = fp82f_sw((unsigned char)((w >> 8) & 0xFF));
    c = fp82f_sw((unsigned char)((w >> 16) & 0xFF));
    d = fp82f_sw((unsigned char)((w >> 24) & 0xFF));
}
#endif

__device__ __forceinline__ float softplus_fast(float x) {
    float t = __expf(-fabsf(x));
    return fmaxf(x, 0.0f) + __logf(1.0f + t);
}

__device__ __forceinline__ float tanh_fast(float x) {
    float t = __expf(-2.0f * fabsf(x));
    float m = (1.0f - t) * __builtin_amdgcn_rcpf(1.0f + t);
    return __builtin_copysignf(m, x);
}

__device__ __forceinline__ int chunk_of(int E) {
    return (((E + NBLK - 1) / NBLK) + 3) & ~3;
}

// ---- 0. intensity -> bf16 + fp8 copies
__global__ __launch_bounds__(256) void cvt_int(const float* __restrict__ x,
                                               unsigned short* __restrict__ ybf,
                                               unsigned* __restrict__ yfp8,
                                               int total4) {
    int t0 = blockIdx.x * 256 + threadIdx.x;
    int stride = gridDim.x * 256;
    for (int i = t0; i < total4; i += stride) {
        float4 v = ((const float4*)x)[i];
        ushort4 r;
        r.x = f2bf(v.x); r.y = f2bf(v.y); r.z = f2bf(v.z); r.w = f2bf(v.w);
        ((ushort4*)ybf)[i] = r;
        yfp8[i] = pack4_fp8(v.x, v.y, v.z, v.w);
    }
}

// ---- 1. per-block bucket histogram: cnt[b*NBLK + blk]
__global__ __launch_bounds__(1024) void bin_count(const int* __restrict__ edst,
                                                  int* __restrict__ cnt,
                                                  int E, int B) {
    __shared__ int lcnt[1024];
    int tid = threadIdx.x, blk = blockIdx.x;
    for (int b = tid; b < B; b += 1024) lcnt[b] = 0;
    __syncthreads();
    int chunk = chunk_of(E);
    int start = blk * chunk;
    int end = min(E, start + chunk);
    int v4s = start >> 2, v4e = end >> 2;
    for (int i = v4s + tid; i < v4e; i += 1024) {
        int4 d = ((const int4*)edst)[i];
        atomicAdd(&lcnt[d.x >> RLOG], 1);
        atomicAdd(&lcnt[d.y >> RLOG], 1);
        atomicAdd(&lcnt[d.z >> RLOG], 1);
        atomicAdd(&lcnt[d.w >> RLOG], 1);
    }
    for (int i = (v4e << 2) + tid; i < end; i += 1024)
        atomicAdd(&lcnt[edst[i] >> RLOG], 1);
    __syncthreads();
    for (int b = tid; b < B; b += 1024) cnt[b * NBLK + blk] = lcnt[b];
}

// ---- 2a. per-block partial sums
__global__ __launch_bounds__(1024) void scan_reduce(const int* __restrict__ cnt,
                                                    int* __restrict__ bsum, int M) {
    int idx = blockIdx.x * 1024 + threadIdx.x;
    int v = (idx < M) ? cnt[idx] : 0;
    #pragma unroll
    for (int off = 32; off; off >>= 1) v += __shfl_xor(v, off);
    __shared__ int wtot[16];
    int lane = threadIdx.x & 63, wave = threadIdx.x >> 6;
    if (lane == 0) wtot[wave] = v;
    __syncthreads();
    if (threadIdx.x == 0) {
        int s = 0;
        #pragma unroll
        for (int i = 0; i < 16; ++i) s += wtot[i];
        bsum[blockIdx.x] = s;
    }
}

// ---- 2b. exclusive scan of block sums (single block, nb <= 1024)
__global__ __launch_bounds__(1024) void scan_top(int* __restrict__ bsum, int nb) {
    int t = threadIdx.x;
    int lane = t & 63, wave = t >> 6;
    int v = (t < nb) ? bsum[t] : 0;
    int incl = v;
    #pragma unroll
    for (int off = 1; off < 64; off <<= 1) {
        int w = __shfl_up(incl, off);
        if (lane >= off) incl += w;
    }
    __shared__ int wt[16];
    if (lane == 63) wt[wave] = incl;
    __syncthreads();
    int woff = 0;
    for (int i = 0; i < wave; ++i) woff += wt[i];
    if (t < nb) bsum[t] = woff + incl - v;
}

// ---- 2c. final exclusive scan -> offs
__global__ __launch_bounds__(1024) void scan_final(const int* __restrict__ cnt,
                                                   const int* __restrict__ bsum,
                                                   int* __restrict__ offs, int M) {
    int t = threadIdx.x;
    int idx = blockIdx.x * 1024 + t;
    int lane = t & 63, wave = t >> 6;
    int v = (idx < M) ? cnt[idx] : 0;
    int incl = v;
    #pragma unroll
    for (int off = 1; off < 64; off <<= 1) {
        int w = __shfl_up(incl, off);
        if (lane >= off) incl += w;
    }
    __shared__ int wtot[16];
    if (lane == 63) wtot[wave] = incl;
    __syncthreads();
    int woff = 0;
    for (int i = 0; i < wave; ++i) woff += wtot[i];
    if (idx < M) offs[idx] = bsum[blockIdx.x] + woff + incl - v;
}

// ---- 3. scatter via LDS-staged block-local counting sort (coalesced out)
__global__ __launch_bounds__(1024) void bin_scatter(const int* __restrict__ esrc,
                                                    const int* __restrict__ edst,
                                                    const int* __restrict__ cnt,
                                                    const int* __restrict__ offs,
                                                    int* __restrict__ binned,
                                                    int E, int B) {
    __shared__ unsigned sl_pack[CHUNK];          // staged packed entries
    __shared__ unsigned short sl_bkt[CHUNK];     // staged bucket ids
    __shared__ int lsc[1024];                    // local excl start -> cursor
    __shared__ int base[1024];                   // goff[b] - lstart[b]
    __shared__ int wtot[16];
    int tid = threadIdx.x, blk = blockIdx.x;
    int lane = tid & 63, wave = tid >> 6;

    // A: reload this block's bucket counts (produced by bin_count)
    int v = (tid < B) ? cnt[tid * NBLK + blk] : 0;
    // B: block exclusive scan over bucket ids
    int incl = v;
    #pragma unroll
    for (int off = 1; off < 64; off <<= 1) {
        int w = __shfl_up(incl, off);
        if (lane >= off) incl += w;
    }
    if (lane == 63) wtot[wave] = incl;
    __syncthreads();
    int woff = 0;
    for (int i = 0; i < wave; ++i) woff += wtot[i];
    int excl = woff + incl - v;
    if (tid < B) {
        base[tid] = offs[tid * NBLK + blk] - excl;
        lsc[tid] = excl;
    }
    __syncthreads();

    // C: single pass over edge chunk, stage into LDS sorted by bucket
    int chunk = chunk_of(E);
    int start = blk * chunk;
    int end = min(E, start + chunk);
    int m = end - start;
    int v4s = start >> 2, v4e = end >> 2;
    for (int i = v4s + tid; i < v4e; i += 1024) {
        int4 d = ((const int4*)edst)[i];
        int4 s = ((const int4*)esrc)[i];
        int b0 = d.x >> RLOG, b1 = d.y >> RLOG, b2 = d.z >> RLOG, b3 = d.w >> RLOG;
        int p0 = atomicAdd(&lsc[b0], 1);
        int p1 = atomicAdd(&lsc[b1], 1);
        int p2 = atomicAdd(&lsc[b2], 1);
        int p3 = atomicAdd(&lsc[b3], 1);
        sl_pack[p0] = ((unsigned)(d.x & (RNODES - 1)) << 17) | (unsigned)s.x;
        sl_pack[p1] = ((unsigned)(d.y & (RNODES - 1)) << 17) | (unsigned)s.y;
        sl_pack[p2] = ((unsigned)(d.z & (RNODES - 1)) << 17) | (unsigned)s.z;
        sl_pack[p3] = ((unsigned)(d.w & (RNODES - 1)) << 17) | (unsigned)s.w;
        sl_bkt[p0] = (unsigned short)b0;
        sl_bkt[p1] = (unsigned short)b1;
        sl_bkt[p2] = (unsigned short)b2;
        sl_bkt[p3] = (unsigned short)b3;
    }
    for (int i = (v4e << 2) + tid; i < end; i += 1024) {
        int d = edst[i];
        int s = esrc[i];
        int b = d >> RLOG;
        int p = atomicAdd(&lsc[b], 1);
        sl_pack[p] = ((unsigned)(d & (RNODES - 1)) << 17) | (unsigned)s;
        sl_bkt[p] = (unsigned short)b;
    }
    __syncthreads();

    // D: ordered flush -> coalesced global writes within bucket runs
    for (int i = tid; i < m; i += 1024) {
        binned[base[sl_bkt[i]] + i] = (int)sl_pack[i];
    }
}

// ---- 4. in-place node sort within each bucket
__global__ __launch_bounds__(256) void node_sort(int* __restrict__ binned,
                                                 const int* __restrict__ offs,
                                                 int* __restrict__ nodestart,
                                                 int* __restrict__ degarr,
                                                 int E, int N, int B) {
    __shared__ int sl[CAP];
    __shared__ int c128[RNODES];
    __shared__ int pos[RNODES];
    int tid = threadIdx.x;
    int b = blockIdx.x;
    int start = offs[b * NBLK];
    int end = (b + 1 < B) ? offs[(b + 1) * NBLK] : E;
    int m = min(end - start, CAP);

    for (int i = tid; i < m; i += 256) sl[i] = binned[start + i];
    if (tid < RNODES) c128[tid] = 0;
    __syncthreads();
    for (int i = tid; i < m; i += 256) atomicAdd(&c128[sl[i] >> 17], 1);
    __syncthreads();

    int x = 0, incl = 0;
    if (tid < RNODES) { x = c128[tid]; incl = x; }
    #pragma unroll
    for (int off = 1; off < RNODES; off <<= 1) {
        int y = 0;
        if (tid < RNODES && tid >= off) y = c128[tid - off];
        __syncthreads();
        if (tid < RNODES) { incl += y; c128[tid] = incl; }
        __syncthreads();
    }
    if (tid < RNODES) {
        int excl = incl - x;
        pos[tid] = excl;
        int node = b * RNODES + tid;
        if (node < N) {
            nodestart[node] = start + excl;
            degarr[node] = x;
        }
    }
    __syncthreads();
    for (int i = tid; i < m; i += 256) {
        int e = sl[i];
        int p = atomicAdd(&pos[e >> 17], 1);
        binned[start + p] = e & 131071;
    }
}

// ---- 5. gather on fp8 rows (32B, L2-resident): 8 lanes/edge, unroll 4
__global__ __launch_bounds__(256) void gather_kernel(
    const unsigned* __restrict__ ifp8, const int* __restrict__ binned,
    const int* __restrict__ nodestart, const int* __restrict__ degarr,
    unsigned short* __restrict__ xnbr, int N) {
    int lane = threadIdx.x & 63;
    int wave = threadIdx.x >> 6;
    int gid = lane >> 3;       // 8 groups of 8 lanes
    int fl = lane & 7;         // uint index within the 32-feature fp8 row
    int gwave = blockIdx.x * 4 + wave;
    int wstride = gridDim.x * 4;
    for (int n = gwave; n < N; n += wstride) {
        int st = nodestart[n];
        int dg = degarr[n];
        float a0 = 0.f, a1 = 0.f, a2 = 0.f, a3 = 0.f;
        int j = gid;
        for (; j + 24 < dg; j += 32) {
            int s0 = binned[st + j];
            int s1 = binned[st + j + 8];
            int s2 = binned[st + j + 16];
            int s3 = binned[st + j + 24];
            unsigned w0 = ifp8[(size_t)s0 * 8 + fl];
            unsigned w1 = ifp8[(size_t)s1 * 8 + fl];
            unsigned w2 = ifp8[(size_t)s2 * 8 + fl];
            unsigned w3 = ifp8[(size_t)s3 * 8 + fl];
            float x0, x1, x2, x3;
            unpack4_fp8(w0, x0, x1, x2, x3);
            a0 += x0; a1 += x1; a2 += x2; a3 += x3;
            unpack4_fp8(w1, x0, x1, x2, x3);
            a0 += x0; a1 += x1; a2 += x2; a3 += x3;
            unpack4_fp8(w2, x0, x1, x2, x3);
            a0 += x0; a1 += x1; a2 += x2; a3 += x3;
            unpack4_fp8(w3, x0, x1, x2, x3);
            a0 += x0; a1 += x1; a2 += x2; a3 += x3;
        }
        for (; j < dg; j += 8) {
            int s0 = binned[st + j];
            unsigned w0 = ifp8[(size_t)s0 * 8 + fl];
            float x0, x1, x2, x3;
            unpack4_fp8(w0, x0, x1, x2, x3);
            a0 += x0; a1 += x1; a2 += x2; a3 += x3;
        }
        #pragma unroll
        for (int off = 8; off < 64; off <<= 1) {
            a0 += __shfl_xor(a0, off);
            a1 += __shfl_xor(a1, off);
            a2 += __shfl_xor(a2, off);
            a3 += __shfl_xor(a3, off);
        }
        if (lane < 8) {
            float inv = (dg > 0) ? 1.0f / (float)dg : 0.0f;
            ushort4 r;
            r.x = f2bf(a0 * inv); r.y = f2bf(a1 * inv);
            r.z = f2bf(a2 * inv); r.w = f2bf(a3 * inv);
            ((ushort4*)xnbr)[(size_t)n * 8 + fl] = r;
        }
    }
}

// ---- 6. build stacked bf16 weight matrix Wbig[192][64]
__global__ __launch_bounds__(256) void prep_w(const float* __restrict__ Wf,
                                              const float* __restrict__ Wg,
                                              const float* __restrict__ Wz,
                                              const float* __restrict__ WA,
                                              unsigned short* __restrict__ wbig) {
    int idx = blockIdx.x * 256 + threadIdx.x;
    if (idx >= 192 * 64) return;
    int r = idx >> 6, k = idx & 63;
    float v = (r < 64)  ? Wf[r * 64 + k]
            : (r < 128) ? Wg[(r - 64) * 64 + k]
            : (r < 160) ? Wz[(r - 128) * 64 + k]
                        : WA[(r - 160) * 64 + k];
    wbig[idx] = f2bf(v);
}

// ---- 7. MFMA node kernel, zero-LDS epilogue in D-fragment layout.
__global__ __launch_bounds__(256, 4) void node_mfma(
    const float* __restrict__ u,
    const unsigned short* __restrict__ ibf,
    const unsigned short* __restrict__ xnbr,
    const unsigned short* __restrict__ wbig,
    const float* __restrict__ bfp, const float* __restrict__ bgp,
    const float* __restrict__ bzp, const float* __restrict__ bAp,
    float* __restrict__ out, int N) {
    int tid = threadIdx.x;
    int lane = tid & 63;
    int wave = tid >> 6;
    int tile = blockIdx.x * 4 + wave;
    int ntiles = N >> 4;
    if (tile >= ntiles) return;

    int col = lane & 15;
    int kg = lane >> 4;
    int n0 = tile * 16;
    int node = n0 + col;

    const float* ub = u + (size_t)node * 64 + kg * 8;
    float4 u0 = *(const float4*)(ub);
    float4 u1 = *(const float4*)(ub + 4);
    float4 u2 = *(const float4*)(ub + 32);
    float4 u3 = *(const float4*)(ub + 36);
    short8 au0, au1;
    au0[0]=(short)f2bf(u0.x); au0[1]=(short)f2bf(u0.y); au0[2]=(short)f2bf(u0.z); au0[3]=(short)f2bf(u0.w);
    au0[4]=(short)f2bf(u1.x); au0[5]=(short)f2bf(u1.y); au0[6]=(short)f2bf(u1.z); au0[7]=(short)f2bf(u1.w);
    au1[0]=(short)f2bf(u2.x); au1[1]=(short)f2bf(u2.y); au1[2]=(short)f2bf(u2.z); au1[3]=(short)f2bf(u2.w);
    au1[4]=(short)f2bf(u3.x); au1[5]=(short)f2bf(u3.y); au1[6]=(short)f2bf(u3.z); au1[7]=(short)f2bf(u3.w);
    short8 ax0 = *(const short8*)(ibf  + (size_t)node * 32 + kg * 8);
    short8 ax1 = *(const short8*)(xnbr + (size_t)node * 32 + kg * 8);

    const short8* wb = (const short8*)wbig;
    f32x4 acc[12];
    #pragma unroll
    for (int t = 0; t < 12; ++t) acc[t] = (f32x4){0.f, 0.f, 0.f, 0.f};
    #pragma unroll
    for (int t = 0; t < 12; ++t) {
        short8 a0 = (t < 10) ? au0 : ax0;
        short8 a1 = (t < 10) ? au1 : ax1;
        short8 b0 = wb[(t * 16 + col) * 8 + kg];
        short8 b1 = wb[(t * 16 + col) * 8 + 4 + kg];
        acc[t] = __builtin_amdgcn_mfma_f32_16x16x32_bf16(a0, b0, acc[t], 0, 0, 0);
        acc[t] = __builtin_amdgcn_mfma_f32_16x16x32_bf16(a1, b1, acc[t], 0, 0, 0);
    }

    float bfv[4], bgv[4], bzv[4];
    #pragma unroll
    for (int s = 0; s < 4; ++s) {
        int j = s * 16 + col;
        bfv[s] = bfp[j];
        bgv[s] = bgp[j];
        bzv[s] = (s < 2) ? bzp[j] : bAp[j - 32];
    }

    float du01[2][4], uv01[2][4];
    float ar[4], br[4];
    #pragma unroll
    for (int r = 0; r < 4; ++r) { ar[r] = 0.f; br[r] = 0.f; }
    #pragma unroll
    for (int s = 0; s < 2; ++s) {
        #pragma unroll
        for (int r = 0; r < 4; ++r) {
            int nd = n0 + kg * 4 + r;
            float uu = u[(size_t)nd * 64 + s * 16 + col];
            float fpre = acc[s][r] + bfv[s];
            float gpre = acc[4 + s][r] + bgv[s];
            float zpre = acc[8 + s][r] + bzv[s];
            float Fu = softplus_fast(fpre);
            float Gu = softplus_fast(gpre);
            float zv = tanh_fast(zpre);
            float d = -Fu * uu + Gu * zv;
            du01[s][r] = d;
            uv01[s][r] = uu;
            ar[r] = fmaf(d, uu, ar[r]);
            br[r] = fmaf(uu, uu, br[r]);
        }
    }
    #pragma unroll
    for (int off = 1; off < 16; off <<= 1) {
        #pragma unroll
        for (int r = 0; r < 4; ++r) {
            ar[r] += __shfl_xor(ar[r], off);
            br[r] += __shfl_xor(br[r], off);
        }
    }
    float coef[4];
    #pragma unroll
    for (int r = 0; r < 4; ++r) coef[r] = ar[r] * __builtin_amdgcn_rcpf(br[r]);

    #pragma unroll
    for (int s = 0; s < 2; ++s) {
        #pragma unroll
        for (int r = 0; r < 4; ++r) {
            int nd = n0 + kg * 4 + r;
            out[(size_t)nd * 64 + s * 16 + col] = du01[s][r] - coef[r] * uv01[s][r];
        }
    }
    #pragma unroll
    for (int s = 2; s < 4; ++s) {
        #pragma unroll
        for (int r = 0; r < 4; ++r) {
            int nd = n0 + kg * 4 + r;
            float uu = u[(size_t)nd * 64 + s * 16 + col];
            float fpre = acc[s][r] + bfv[s];
            float gpre = acc[4 + s][r] + bgv[s];
            float zpre = acc[8 + s][r] + bzv[s];
            float Fu = softplus_fast(fpre);
            float Gu = softplus_fast(gpre);
            float zv = fmaxf(zpre, 0.0f);
            out[(size_t)nd * 64 + s * 16 + col] = -Fu * uu + Gu * zv;
        }
    }
}

extern "C" void kernel_launch(void* const* d_in, const int* in_sizes, int n_in,
                              void* d_out, int out_size, void* d_ws, size_t ws_size,
                              hipStream_t stream) {
    const float* u         = (const float*)d_in[0];
    const float* intensity = (const float*)d_in[1];
    const int*   esrc      = (const int*)d_in[2];
    const int*   edst      = (const int*)d_in[3];
    const float* Wf        = (const float*)d_in[4];
    const float* bf        = (const float*)d_in[5];
    const float* Wg        = (const float*)d_in[6];
    const float* bg        = (const float*)d_in[7];
    const float* Wz        = (const float*)d_in[8];
    const float* bz        = (const float*)d_in[9];
    const float* WA        = (const float*)d_in[10];
    const float* bA        = (const float*)d_in[11];

    int N = in_sizes[0] / 64;
    int E = in_sizes[2];
    int B = (N + RNODES - 1) / RNODES;          // 782
    int M = B * NBLK;                            // 400384
    int nb = (M + 1023) / 1024;                  // 391 (<=1024)

    int* cnt       = (int*)d_ws;                 // M
    int* offs      = cnt + M;                    // M
    int* bsum      = offs + M;                   // 1024
    int* binned    = bsum + 1024;                // E
    int* nodestart = binned + E;                 // N
    int* degarr    = nodestart + N;              // N
    unsigned short* xnbr = (unsigned short*)(degarr + N);   // N*32
    unsigned short* wbig = xnbr + (size_t)N * 32;           // 192*64
    unsigned short* ibf  = wbig + 192 * 64;                 // N*32
    unsigned* ifp8 = (unsigned*)(ibf + (size_t)N * 32);     // N*8 uints

    cvt_int<<<2048, 256, 0, stream>>>(intensity, ibf, ifp8, N * 8);
    prep_w<<<48, 256, 0, stream>>>(Wf, Wg, Wz, WA, wbig);
    bin_count<<<NBLK, 1024, 0, stream>>>(edst, cnt, E, B);
    scan_reduce<<<nb, 1024, 0, stream>>>(cnt, bsum, M);
    scan_top<<<1, 1024, 0, stream>>>(bsum, nb);
    scan_final<<<nb, 1024, 0, stream>>>(cnt, bsum, offs, M);
    bin_scatter<<<NBLK, 1024, 0, stream>>>(esrc, edst, cnt, offs, binned, E, B);
    node_sort<<<B, 256, 0, stream>>>(binned, offs, nodestart, degarr, E, N, B);
    gather_kernel<<<2048, 256, 0, stream>>>(ifp8, binned, nodestart, degarr,
                                            xnbr, N);
    int ntiles = N / 16;
    int nblocks = (ntiles + 3) / 4;
    node_mfma<<<nblocks, 256, 0, stream>>>(u, ibf, xnbr, wbig,
                                           bf, bg, bz, bA, (float*)d_out, N);
}

// Round 14
// 98.039 us; speedup vs baseline: 1.4657x; 1.3364x over previous
//
#include <hip/hip_runtime.h>

// N=100000 nodes, D=64, P=Q=32, E=3200000 edges.
// 6-dispatch pipeline:
//  1. prep_count   : bin_count (512 blks) + intensity->bf16/fp8 (64) + Wbig (1)
//  2. scanA        : per-bucket scan of 512 per-block counts -> lofs, T[b]
//  3. scanB        : exclusive scan of bucket totals T -> G
//  4. bin_scatter  : LDS counting-sort scatter, coalesced writes (offs = G+lofs)
//  5. bucket_fused : node-sort in LDS + per-node fp8 gather from LDS list -> xnbr
//  6. node_mfma    : bf16 MFMA + zero-LDS D-fragment epilogue

#define RLOG 7
#define RNODES 128
#define NBLK 512
#define CAP 6144
#define CHUNK 6272   // >= ceil4(E/NBLK) = 6252
#define CVB 64       // cvt blocks inside prep_count

typedef __attribute__((ext_vector_type(8))) short short8;
typedef __attribute__((ext_vector_type(4))) float f32x4;
typedef __attribute__((ext_vector_type(2))) float f32x2;

__device__ __forceinline__ unsigned short f2bf(float x) {
    union { float f; unsigned u; } v; v.f = x;
    unsigned r = v.u + 0x7FFF + ((v.u >> 16) & 1);  // RNE
    return (unsigned short)(r >> 16);
}

// ---- fp8 pack/unpack: prefer HW cvt (self-consistent encode/decode) ----
#if __has_builtin(__builtin_amdgcn_cvt_pk_fp8_f32) && __has_builtin(__builtin_amdgcn_cvt_pk_f32_fp8)
__device__ __forceinline__ unsigned pack4_fp8(float a, float b, float c, float d) {
    int p = __builtin_amdgcn_cvt_pk_fp8_f32(a, b, 0, false);
    p = __builtin_amdgcn_cvt_pk_fp8_f32(c, d, p, true);
    return (unsigned)p;
}
__device__ __forceinline__ void unpack4_fp8(unsigned w, float& a, float& b, float& c, float& d) {
    f32x2 lo = __builtin_amdgcn_cvt_pk_f32_fp8(w, false);
    f32x2 hi = __builtin_amdgcn_cvt_pk_f32_fp8(w, true);
    a = lo[0]; b = lo[1]; c = hi[0]; d = hi[1];
}
#else
__device__ __forceinline__ unsigned char f2fp8_sw(float x) {
    union { float f; unsigned u; } v; v.f = x;
    unsigned s = (v.u >> 24) & 0x80;
    float ax = fminf(fabsf(x), 448.0f);
    union { float f; unsigned u; } w; w.f = ax;
    int e = (int)((w.u >> 23) & 0xFF) - 127;
    if (e < -6) {
        int mi = (int)(ax * 512.0f + 0.5f);
        if (mi > 7) mi = 7;
        return (unsigned char)(s | mi);
    }
    unsigned mant = (w.u >> 20) & 7;
    unsigned rest = w.u & 0xFFFFF;
    unsigned rnd = (rest > 0x80000u) || (rest == 0x80000u && (mant & 1));
    unsigned enc = ((unsigned)(e + 7) << 3) | mant;
    enc += rnd;
    if (enc > 0x7Eu) enc = 0x7Eu;
    return (unsigned char)(s | enc);
}
__device__ __forceinline__ float fp82f_sw(unsigned char b) {
    unsigned e = (b >> 3) & 0xF, m = b & 7;
    float mag;
    if (e == 0) mag = (float)m * 0.001953125f;
    else {
        union { unsigned u; float f; } v;
        v.u = ((e + 120u) << 23) | (m << 20);
        mag = v.f;
    }
    return (b & 0x80) ? -mag : mag;
}
__device__ __forceinline__ unsigned pack4_fp8(float a, float b, float c, float d) {
    return (unsigned)f2fp8_sw(a) | ((unsigned)f2fp8_sw(b) << 8) |
           ((unsigned)f2fp8_sw(c) << 16) | ((unsigned)f2fp8_sw(d) << 24);
}
__device__ __forceinline__ void unpack4_fp8(unsigned w, float& a, float& b, float& c, float& d) {
    a = fp82f_sw((unsigned char)(w & 0xFF));
    b = fp82f_sw((unsigned char)((w >> 8) & 0xFF));
    c = fp82f_sw((unsigned char)((w >> 16) & 0xFF));
    d = fp82f_sw((unsigned char)((w >> 24) & 0xFF));
}
#endif

__device__ __forceinline__ float softplus_fast(float x) {
    float t = __expf(-fabsf(x));
    return fmaxf(x, 0.0f) + __logf(1.0f + t);
}

__device__ __forceinline__ float tanh_fast(float x) {
    float t = __expf(-2.0f * fabsf(x));
    float m = (1.0f - t) * __builtin_amdgcn_rcpf(1.0f + t);
    return __builtin_copysignf(m, x);
}

__device__ __forceinline__ int chunk_of(int E) {
    return (((E + NBLK - 1) / NBLK) + 3) & ~3;
}

// ---- 1. fused prep: bin_count | intensity cvt | weight stack
__global__ __launch_bounds__(1024) void prep_count(
    const int* __restrict__ edst, int* __restrict__ cnt,
    const float* __restrict__ x, unsigned short* __restrict__ ybf,
    unsigned* __restrict__ yfp8, int total4,
    const float* __restrict__ Wf, const float* __restrict__ Wg,
    const float* __restrict__ Wz, const float* __restrict__ WA,
    unsigned short* __restrict__ wbig,
    int E, int B) {
    int tid = threadIdx.x, blk = blockIdx.x;
    if (blk < NBLK) {
        // --- histogram of bucket ids for this block's edge chunk ---
        __shared__ int lcnt[1024];
        for (int b = tid; b < B; b += 1024) lcnt[b] = 0;
        __syncthreads();
        int chunk = chunk_of(E);
        int start = blk * chunk;
        int end = min(E, start + chunk);
        int v4s = start >> 2, v4e = end >> 2;
        for (int i = v4s + tid; i < v4e; i += 1024) {
            int4 d = ((const int4*)edst)[i];
            atomicAdd(&lcnt[d.x >> RLOG], 1);
            atomicAdd(&lcnt[d.y >> RLOG], 1);
            atomicAdd(&lcnt[d.z >> RLOG], 1);
            atomicAdd(&lcnt[d.w >> RLOG], 1);
        }
        for (int i = (v4e << 2) + tid; i < end; i += 1024)
            atomicAdd(&lcnt[edst[i] >> RLOG], 1);
        __syncthreads();
        for (int b = tid; b < B; b += 1024) cnt[b * NBLK + blk] = lcnt[b];
    } else if (blk < NBLK + CVB) {
        // --- intensity -> bf16 + fp8 ---
        int cb = blk - NBLK;
        for (int i = cb * 1024 + tid; i < total4; i += CVB * 1024) {
            float4 v = ((const float4*)x)[i];
            ushort4 r;
            r.x = f2bf(v.x); r.y = f2bf(v.y); r.z = f2bf(v.z); r.w = f2bf(v.w);
            ((ushort4*)ybf)[i] = r;
            yfp8[i] = pack4_fp8(v.x, v.y, v.z, v.w);
        }
    } else {
        // --- stacked bf16 weight matrix Wbig[192][64] ---
        for (int idx = tid; idx < 192 * 64; idx += 1024) {
            int r = idx >> 6, k = idx & 63;
            float v = (r < 64)  ? Wf[r * 64 + k]
                    : (r < 128) ? Wg[(r - 64) * 64 + k]
                    : (r < 160) ? Wz[(r - 128) * 64 + k]
                                : WA[(r - 160) * 64 + k];
            wbig[idx] = f2bf(v);
        }
    }
}

// ---- 2. scanA: per-bucket exclusive scan over NBLK per-block counts
__global__ __launch_bounds__(512) void scanA(const int* __restrict__ cnt,
                                             int* __restrict__ lofs,
                                             int* __restrict__ T) {
    int t = threadIdx.x, b = blockIdx.x;
    int lane = t & 63, wave = t >> 6;   // 8 waves
    int v = cnt[b * NBLK + t];
    int incl = v;
    #pragma unroll
    for (int off = 1; off < 64; off <<= 1) {
        int w = __shfl_up(incl, off);
        if (lane >= off) incl += w;
    }
    __shared__ int wt[8];
    if (lane == 63) wt[wave] = incl;
    __syncthreads();
    int woff = 0;
    for (int i = 0; i < wave; ++i) woff += wt[i];
    int excl = woff + incl - v;
    lofs[b * NBLK + t] = excl;
    if (t == NBLK - 1) T[b] = excl + v;
}

// ---- 3. scanB: exclusive scan of bucket totals (B <= 1024, one block)
__global__ __launch_bounds__(1024) void scanB(const int* __restrict__ T,
                                              int* __restrict__ G, int B) {
    int t = threadIdx.x;
    int lane = t & 63, wave = t >> 6;
    int v = (t < B) ? T[t] : 0;
    int incl = v;
    #pragma unroll
    for (int off = 1; off < 64; off <<= 1) {
        int w = __shfl_up(incl, off);
        if (lane >= off) incl += w;
    }
    __shared__ int wt[16];
    if (lane == 63) wt[wave] = incl;
    __syncthreads();
    int woff = 0;
    for (int i = 0; i < wave; ++i) woff += wt[i];
    if (t < B) G[t] = woff + incl - v;
}

// ---- 4. scatter via LDS-staged block-local counting sort (coalesced out)
__global__ __launch_bounds__(1024) void bin_scatter(const int* __restrict__ esrc,
                                                    const int* __restrict__ edst,
                                                    const int* __restrict__ cnt,
                                                    const int* __restrict__ lofs,
                                                    const int* __restrict__ G,
                                                    int* __restrict__ binned,
                                                    int E, int B) {
    __shared__ unsigned sl_pack[CHUNK];
    __shared__ unsigned short sl_bkt[CHUNK];
    __shared__ int lsc[1024];
    __shared__ int base[1024];
    __shared__ int wtot[16];
    int tid = threadIdx.x, blk = blockIdx.x;
    int lane = tid & 63, wave = tid >> 6;

    int v = (tid < B) ? cnt[tid * NBLK + blk] : 0;
    int incl = v;
    #pragma unroll
    for (int off = 1; off < 64; off <<= 1) {
        int w = __shfl_up(incl, off);
        if (lane >= off) incl += w;
    }
    if (lane == 63) wtot[wave] = incl;
    __syncthreads();
    int woff = 0;
    for (int i = 0; i < wave; ++i) woff += wtot[i];
    int excl = woff + incl - v;
    if (tid < B) {
        base[tid] = G[tid] + lofs[tid * NBLK + blk] - excl;
        lsc[tid] = excl;
    }
    __syncthreads();

    int chunk = chunk_of(E);
    int start = blk * chunk;
    int end = min(E, start + chunk);
    int m = end - start;
    int v4s = start >> 2, v4e = end >> 2;
    for (int i = v4s + tid; i < v4e; i += 1024) {
        int4 d = ((const int4*)edst)[i];
        int4 s = ((const int4*)esrc)[i];
        int b0 = d.x >> RLOG, b1 = d.y >> RLOG, b2 = d.z >> RLOG, b3 = d.w >> RLOG;
        int p0 = atomicAdd(&lsc[b0], 1);
        int p1 = atomicAdd(&lsc[b1], 1);
        int p2 = atomicAdd(&lsc[b2], 1);
        int p3 = atomicAdd(&lsc[b3], 1);
        sl_pack[p0] = ((unsigned)(d.x & (RNODES - 1)) << 17) | (unsigned)s.x;
        sl_pack[p1] = ((unsigned)(d.y & (RNODES - 1)) << 17) | (unsigned)s.y;
        sl_pack[p2] = ((unsigned)(d.z & (RNODES - 1)) << 17) | (unsigned)s.z;
        sl_pack[p3] = ((unsigned)(d.w & (RNODES - 1)) << 17) | (unsigned)s.w;
        sl_bkt[p0] = (unsigned short)b0;
        sl_bkt[p1] = (unsigned short)b1;
        sl_bkt[p2] = (unsigned short)b2;
        sl_bkt[p3] = (unsigned short)b3;
    }
    for (int i = (v4e << 2) + tid; i < end; i += 1024) {
        int d = edst[i];
        int s = esrc[i];
        int b = d >> RLOG;
        int p = atomicAdd(&lsc[b], 1);
        sl_pack[p] = ((unsigned)(d & (RNODES - 1)) << 17) | (unsigned)s;
        sl_bkt[p] = (unsigned short)b;
    }
    __syncthreads();

    for (int i = tid; i < m; i += 1024) {
        binned[base[sl_bkt[i]] + i] = (int)sl_pack[i];
    }
}

// ---- 5. fused: node sort (LDS) + per-node fp8 gather from LDS list
__global__ __launch_bounds__(1024) void bucket_fused(
    const int* __restrict__ binned, const int* __restrict__ G,
    const unsigned* __restrict__ ifp8,
    unsigned short* __restrict__ xnbr, int E, int N, int B) {
    __shared__ int sl[CAP];       // staged packed entries
    __shared__ int sl2[CAP];      // node-sorted src ids
    __shared__ int c128[RNODES];
    __shared__ int pos[RNODES];
    __shared__ int dstart[RNODES];
    __shared__ int ddeg[RNODES];
    int tid = threadIdx.x;
    int b = blockIdx.x;
    int start = G[b];
    int end = (b + 1 < B) ? G[b + 1] : E;
    int m = min(end - start, CAP);

    for (int i = tid; i < m; i += 1024) sl[i] = binned[start + i];
    if (tid < RNODES) c128[tid] = 0;
    __syncthreads();
    for (int i = tid; i < m; i += 1024) atomicAdd(&c128[sl[i] >> 17], 1);
    __syncthreads();

    // Hillis-Steele inclusive scan over 128 counts
    int x = 0, incl = 0;
    if (tid < RNODES) { x = c128[tid]; incl = x; }
    #pragma unroll
    for (int off = 1; off < RNODES; off <<= 1) {
        int y = 0;
        if (tid < RNODES && tid >= off) y = c128[tid - off];
        __syncthreads();
        if (tid < RNODES) { incl += y; c128[tid] = incl; }
        __syncthreads();
    }
    if (tid < RNODES) {
        int excl = incl - x;
        pos[tid] = excl;
        dstart[tid] = excl;
        ddeg[tid] = x;
    }
    __syncthreads();
    for (int i = tid; i < m; i += 1024) {
        int e = sl[i];
        int p = atomicAdd(&pos[e >> 17], 1);
        sl2[p] = e & 131071;
    }
    __syncthreads();

    // gather: 128 groups of 8 lanes; group g = local node g; lane owns 4 features
    int g = tid >> 3;
    int fl = tid & 7;
    int node = b * RNODES + g;
    int st = dstart[g];
    int dg = ddeg[g];
    float a0 = 0.f, a1 = 0.f, a2 = 0.f, a3 = 0.f;
    int j = 0;
    for (; j + 3 < dg; j += 4) {
        int s0 = sl2[st + j];      // broadcast within group
        int s1 = sl2[st + j + 1];
        int s2 = sl2[st + j + 2];
        int s3 = sl2[st + j + 3];
        unsigned w0 = ifp8[(size_t)s0 * 8 + fl];
        unsigned w1 = ifp8[(size_t)s1 * 8 + fl];
        unsigned w2 = ifp8[(size_t)s2 * 8 + fl];
        unsigned w3 = ifp8[(size_t)s3 * 8 + fl];
        float x0, x1, x2, x3;
        unpack4_fp8(w0, x0, x1, x2, x3);
        a0 += x0; a1 += x1; a2 += x2; a3 += x3;
        unpack4_fp8(w1, x0, x1, x2, x3);
        a0 += x0; a1 += x1; a2 += x2; a3 += x3;
        unpack4_fp8(w2, x0, x1, x2, x3);
        a0 += x0; a1 += x1; a2 += x2; a3 += x3;
        unpack4_fp8(w3, x0, x1, x2, x3);
        a0 += x0; a1 += x1; a2 += x2; a3 += x3;
    }
    for (; j < dg; ++j) {
        int s0 = sl2[st + j];
        unsigned w0 = ifp8[(size_t)s0 * 8 + fl];
        float x0, x1, x2, x3;
        unpack4_fp8(w0, x0, x1, x2, x3);
        a0 += x0; a1 += x1; a2 += x2; a3 += x3;
    }
    if (node < N) {
        float inv = (dg > 0) ? 1.0f / (float)dg : 0.0f;
        ushort4 r;
        r.x = f2bf(a0 * inv); r.y = f2bf(a1 * inv);
        r.z = f2bf(a2 * inv); r.w = f2bf(a3 * inv);
        ((ushort4*)xnbr)[(size_t)node * 8 + fl] = r;
    }
}

// ---- 6. MFMA node kernel, zero-LDS epilogue in D-fragment layout.
__global__ __launch_bounds__(256, 4) void node_mfma(
    const float* __restrict__ u,
    const unsigned short* __restrict__ ibf,
    const unsigned short* __restrict__ xnbr,
    const unsigned short* __restrict__ wbig,
    const float* __restrict__ bfp, const float* __restrict__ bgp,
    const float* __restrict__ bzp, const float* __restrict__ bAp,
    float* __restrict__ out, int N) {
    int tid = threadIdx.x;
    int lane = tid & 63;
    int wave = tid >> 6;
    int tile = blockIdx.x * 4 + wave;
    int ntiles = N >> 4;
    if (tile >= ntiles) return;

    int col = lane & 15;
    int kg = lane >> 4;
    int n0 = tile * 16;
    int node = n0 + col;

    const float* ub = u + (size_t)node * 64 + kg * 8;
    float4 u0 = *(const float4*)(ub);
    float4 u1 = *(const float4*)(ub + 4);
    float4 u2 = *(const float4*)(ub + 32);
    float4 u3 = *(const float4*)(ub + 36);
    short8 au0, au1;
    au0[0]=(short)f2bf(u0.x); au0[1]=(short)f2bf(u0.y); au0[2]=(short)f2bf(u0.z); au0[3]=(short)f2bf(u0.w);
    au0[4]=(short)f2bf(u1.x); au0[5]=(short)f2bf(u1.y); au0[6]=(short)f2bf(u1.z); au0[7]=(short)f2bf(u1.w);
    au1[0]=(short)f2bf(u2.x); au1[1]=(short)f2bf(u2.y); au1[2]=(short)f2bf(u2.z); au1[3]=(short)f2bf(u2.w);
    au1[4]=(short)f2bf(u3.x); au1[5]=(short)f2bf(u3.y); au1[6]=(short)f2bf(u3.z); au1[7]=(short)f2bf(u3.w);
    short8 ax0 = *(const short8*)(ibf  + (size_t)node * 32 + kg * 8);
    short8 ax1 = *(const short8*)(xnbr + (size_t)node * 32 + kg * 8);

    const short8* wb = (const short8*)wbig;
    f32x4 acc[12];
    #pragma unroll
    for (int t = 0; t < 12; ++t) acc[t] = (f32x4){0.f, 0.f, 0.f, 0.f};
    #pragma unroll
    for (int t = 0; t < 12; ++t) {
        short8 a0 = (t < 10) ? au0 : ax0;
        short8 a1 = (t < 10) ? au1 : ax1;
        short8 b0 = wb[(t * 16 + col) * 8 + kg];
        short8 b1 = wb[(t * 16 + col) * 8 + 4 + kg];
        acc[t] = __builtin_amdgcn_mfma_f32_16x16x32_bf16(a0, b0, acc[t], 0, 0, 0);
        acc[t] = __builtin_amdgcn_mfma_f32_16x16x32_bf16(a1, b1, acc[t], 0, 0, 0);
    }

    float bfv[4], bgv[4], bzv[4];
    #pragma unroll
    for (int s = 0; s < 4; ++s) {
        int j = s * 16 + col;
        bfv[s] = bfp[j];
        bgv[s] = bgp[j];
        bzv[s] = (s < 2) ? bzp[j] : bAp[j - 32];
    }

    float du01[2][4], uv01[2][4];
    float ar[4], br[4];
    #pragma unroll
    for (int r = 0; r < 4; ++r) { ar[r] = 0.f; br[r] = 0.f; }
    #pragma unroll
    for (int s = 0; s < 2; ++s) {
        #pragma unroll
        for (int r = 0; r < 4; ++r) {
            int nd = n0 + kg * 4 + r;
            float uu = u[(size_t)nd * 64 + s * 16 + col];
            float fpre = acc[s][r] + bfv[s];
            float gpre = acc[4 + s][r] + bgv[s];
            float zpre = acc[8 + s][r] + bzv[s];
            float Fu = softplus_fast(fpre);
            float Gu = softplus_fast(gpre);
            float zv = tanh_fast(zpre);
            float d = -Fu * uu + Gu * zv;
            du01[s][r] = d;
            uv01[s][r] = uu;
            ar[r] = fmaf(d, uu, ar[r]);
            br[r] = fmaf(uu, uu, br[r]);
        }
    }
    #pragma unroll
    for (int off = 1; off < 16; off <<= 1) {
        #pragma unroll
        for (int r = 0; r < 4; ++r) {
            ar[r] += __shfl_xor(ar[r], off);
            br[r] += __shfl_xor(br[r], off);
        }
    }
    float coef[4];
    #pragma unroll
    for (int r = 0; r < 4; ++r) coef[r] = ar[r] * __builtin_amdgcn_rcpf(br[r]);

    #pragma unroll
    for (int s = 0; s < 2; ++s) {
        #pragma unroll
        for (int r = 0; r < 4; ++r) {
            int nd = n0 + kg * 4 + r;
            out[(size_t)nd * 64 + s * 16 + col] = du01[s][r] - coef[r] * uv01[s][r];
        }
    }
    #pragma unroll
    for (int s = 2; s < 4; ++s) {
        #pragma unroll
        for (int r = 0; r < 4; ++r) {
            int nd = n0 + kg * 4 + r;
            float uu = u[(size_t)nd * 64 + s * 16 + col];
            float fpre = acc[s][r] + bfv[s];
            float gpre = acc[4 + s][r] + bgv[s];
            float zpre = acc[8 + s][r] + bzv[s];
            float Fu = softplus_fast(fpre);
            float Gu = softplus_fast(gpre);
            float zv = fmaxf(zpre, 0.0f);
            out[(size_t)nd * 64 + s * 16 + col] = -Fu * uu + Gu * zv;
        }
    }
}

extern "C" void kernel_launch(void* const* d_in, const int* in_sizes, int n_in,
                              void* d_out, int out_size, void* d_ws, size_t ws_size,
                              hipStream_t stream) {
    const float* u         = (const float*)d_in[0];
    const float* intensity = (const float*)d_in[1];
    const int*   esrc      = (const int*)d_in[2];
    const int*   edst      = (const int*)d_in[3];
    const float* Wf        = (const float*)d_in[4];
    const float* bf        = (const float*)d_in[5];
    const float* Wg        = (const float*)d_in[6];
    const float* bg        = (const float*)d_in[7];
    const float* Wz        = (const float*)d_in[8];
    const float* bz        = (const float*)d_in[9];
    const float* WA        = (const float*)d_in[10];
    const float* bA        = (const float*)d_in[11];

    int N = in_sizes[0] / 64;
    int E = in_sizes[2];
    int B = (N + RNODES - 1) / RNODES;          // 782
    int M = B * NBLK;                            // 400384

    int* cnt    = (int*)d_ws;                    // M
    int* lofs   = cnt + M;                       // M
    int* T      = lofs + M;                      // 1024
    int* G      = T + 1024;                      // 1024
    int* binned = G + 1024;                      // E
    unsigned short* xnbr = (unsigned short*)(binned + E);   // N*32
    unsigned short* wbig = xnbr + (size_t)N * 32;           // 192*64
    unsigned short* ibf  = wbig + 192 * 64;                 // N*32
    unsigned* ifp8 = (unsigned*)(ibf + (size_t)N * 32);     // N*8 uints

    prep_count<<<NBLK + CVB + 1, 1024, 0, stream>>>(
        edst, cnt, intensity, ibf, ifp8, N * 8, Wf, Wg, Wz, WA, wbig, E, B);
    scanA<<<B, 512, 0, stream>>>(cnt, lofs, T);
    scanB<<<1, 1024, 0, stream>>>(T, G, B);
    bin_scatter<<<NBLK, 1024, 0, stream>>>(esrc, edst, cnt, lofs, G, binned, E, B);
    bucket_fused<<<B, 1024, 0, stream>>>(binned, G, ifp8, xnbr, E, N, B);
    int ntiles = N / 16;
    int nblocks = (ntiles + 3) / 4;
    node_mfma<<<nblocks, 256, 0, stream>>>(u, ibf, xnbr, wbig,
                                           bf, bg, bz, bA, (float*)d_out, N);
}